// Round 1
// baseline (3231.210 us; speedup 1.0000x reference)
//
#include <hip/hip_runtime.h>
#include <hip/hip_bf16.h>
#include <cstddef>

// ---------------- GEMM: C[M,N] = A[M,K] @ B[K,N], fp32, row-major ----------------
// BM=BN=128, BK=16, 256 threads, 8x8 microtile per thread.
#define BM 128
#define BN 128
#define BK 16
#define TM 8
#define TN 8

__global__ __launch_bounds__(256) void gemm_f32(
    const float* __restrict__ A, const float* __restrict__ B, float* __restrict__ C,
    int M, int N, int K) {
  __shared__ float As[BK][BM];
  __shared__ float Bs[BK][BN];
  const int tid = threadIdx.x;
  const int brow = blockIdx.y * BM;
  const int bcol = blockIdx.x * BN;
  const int tr = (tid / (BN / TN)) * TM;  // 0..120
  const int tc = (tid % (BN / TN)) * TN;  // 0..120
  float acc[TM][TN] = {};

  for (int k0 = 0; k0 < K; k0 += BK) {
    // A tile: 128 rows x 16 cols. thread t -> m = t/2, k = (t&1)*8 (two float4)
    {
      const int m = tid >> 1;
      const int k = (tid & 1) * 8;
      const int gr = brow + m;
      float4 v0 = make_float4(0.f, 0.f, 0.f, 0.f), v1 = v0;
      if (gr < M) {
        const float* p = A + (size_t)gr * K + k0 + k;
        v0 = *(const float4*)p;
        v1 = *(const float4*)(p + 4);
      }
      As[k + 0][m] = v0.x; As[k + 1][m] = v0.y; As[k + 2][m] = v0.z; As[k + 3][m] = v0.w;
      As[k + 4][m] = v1.x; As[k + 5][m] = v1.y; As[k + 6][m] = v1.z; As[k + 7][m] = v1.w;
    }
    // B tile: 16 rows x 128 cols. thread t -> k = t/16, n = (t&15)*8
    {
      const int k = tid >> 4;
      const int n = (tid & 15) * 8;
      const float* p = B + (size_t)(k0 + k) * N + bcol + n;
      float4 v0 = *(const float4*)p;
      float4 v1 = *(const float4*)(p + 4);
      *(float4*)&Bs[k][n] = v0;
      *(float4*)&Bs[k][n + 4] = v1;
    }
    __syncthreads();
#pragma unroll
    for (int k = 0; k < BK; ++k) {
      float a[TM], b[TN];
      *(float4*)&a[0] = *(const float4*)&As[k][tr];
      *(float4*)&a[4] = *(const float4*)&As[k][tr + 4];
      *(float4*)&b[0] = *(const float4*)&Bs[k][tc];
      *(float4*)&b[4] = *(const float4*)&Bs[k][tc + 4];
#pragma unroll
      for (int i = 0; i < TM; i++)
#pragma unroll
        for (int j = 0; j < TN; j++)
          acc[i][j] = fmaf(a[i], b[j], acc[i][j]);
    }
    __syncthreads();
  }

  for (int i = 0; i < TM; i++) {
    const int gr = brow + tr + i;
    if (gr < M) {
      float4* p = (float4*)(C + (size_t)gr * N + bcol + tc);
      p[0] = *(float4*)&acc[i][0];
      p[1] = *(float4*)&acc[i][4];
    }
  }
}

// ---------------- residual init copy (float4 grid-stride-free) ----------------
__global__ __launch_bounds__(256) void copy_f32v4(const float* __restrict__ src,
                                                  float* __restrict__ dst, int n4) {
  int i = blockIdx.x * 256 + threadIdx.x;
  if (i < n4) ((float4*)dst)[i] = ((const float4*)src)[i];
}

// ---------------- edge scatter: acc[row[e]] += ew[e] * hp[col[e]] ----------------
// 4 edges per block, one wave (64 lanes) per edge, 256 features per row.
__global__ __launch_bounds__(256) void scatter_edges(
    const float* __restrict__ hp, const float* __restrict__ ew,
    const int* __restrict__ row, const int* __restrict__ col,
    float* __restrict__ acc, int E) {
  const int wave = threadIdx.x >> 6;
  const int lane = threadIdx.x & 63;
  const int e = blockIdx.x * 4 + wave;
  if (e >= E) return;
  const int r = row[e];
  const int c = col[e];
  const float w = ew[e];
  const float* __restrict__ src = hp + (size_t)c * 256;
  float* __restrict__ dst = acc + (size_t)r * 256;
#pragma unroll
  for (int j = 0; j < 4; ++j) {
    const int f = j * 64 + lane;
    atomicAdd(dst + f, w * src[f]);
  }
}

// ---------------- in-place LayerNorm over D=256, one wave per row ----------------
__global__ __launch_bounds__(256) void ln_rows(
    float* __restrict__ io, const float* __restrict__ g, const float* __restrict__ b,
    int nrows) {
  const int wave = threadIdx.x >> 6;
  const int lane = threadIdx.x & 63;
  const int r = blockIdx.x * 4 + wave;
  if (r >= nrows) return;
  float* p = io + (size_t)r * 256;
  float v[4];
  float s = 0.f;
#pragma unroll
  for (int j = 0; j < 4; j++) {
    v[j] = p[j * 64 + lane];
    s += v[j];
  }
#pragma unroll
  for (int m = 32; m >= 1; m >>= 1) s += __shfl_xor(s, m);
  const float mu = s * (1.f / 256.f);
  float ss = 0.f;
#pragma unroll
  for (int j = 0; j < 4; j++) {
    v[j] -= mu;
    ss += v[j] * v[j];
  }
#pragma unroll
  for (int m = 32; m >= 1; m >>= 1) ss += __shfl_xor(ss, m);
  const float rs = rsqrtf(ss * (1.f / 256.f) + 1e-5f);
#pragma unroll
  for (int j = 0; j < 4; j++) {
    const int f = j * 64 + lane;
    p[f] = v[j] * rs * g[f] + b[f];
  }
}

extern "C" void kernel_launch(void* const* d_in, const int* in_sizes, int n_in,
                              void* d_out, int out_size, void* d_ws, size_t ws_size,
                              hipStream_t stream) {
  const float* x0    = (const float*)d_in[0];
  const float* x1    = (const float*)d_in[1];
  const float* W0    = (const float*)d_in[2];
  const float* W1    = (const float*)d_in[3];
  const float* Wres1 = (const float*)d_in[4];
  const float* g0    = (const float*)d_in[5];
  const float* b0    = (const float*)d_in[6];
  const float* g1    = (const float*)d_in[7];
  const float* b1    = (const float*)d_in[8];
  const float* ew0   = (const float*)d_in[9];
  const float* ew1   = (const float*)d_in[10];
  const int*   row0  = (const int*)d_in[11];
  const int*   col0  = (const int*)d_in[12];
  const int*   row1  = (const int*)d_in[13];
  const int*   col1  = (const int*)d_in[14];
  float* out = (float*)d_out;

  const int N0 = 50000, N1 = 50000, D0 = 256, D1 = 512, DO = 256, E = 1600000;

  float* hp = (float*)d_ws;  // 50000*256 fp32 = 51.2 MB scratch, reused per type

  float* out0 = out;                       // rows [0, 50000)
  float* out1 = out + (size_t)N0 * DO;     // rows [50000, 100000)

  const dim3 blk(256);
  const dim3 gemm_grid(DO / BN, (N0 + BM - 1) / BM);  // (2, 391)
  const dim3 edge_grid((E + 3) / 4);
  const dim3 ln_grid((N0 + 3) / 4);

  // ---- type 0: identity residual ----
  // out0 = x0 (residual init; scatter accumulates on top)
  copy_f32v4<<<dim3((N0 * DO / 4 + 255) / 256), blk, 0, stream>>>(x0, out0, N0 * DO / 4);
  // hp = x0 @ W0
  gemm_f32<<<gemm_grid, blk, 0, stream>>>(x0, W0, hp, N0, DO, D0);
  // out0 += segment_sum(ew0 * hp[col0], row0)
  scatter_edges<<<edge_grid, blk, 0, stream>>>(hp, ew0, row0, col0, out0, E);
  // out0 = LN(out0)
  ln_rows<<<ln_grid, blk, 0, stream>>>(out0, g0, b0, N0);

  // ---- type 1: projected residual ----
  // out1 = x1 @ Wres1 (residual init)
  gemm_f32<<<gemm_grid, blk, 0, stream>>>(x1, Wres1, out1, N1, DO, D1);
  // hp = x1 @ W1
  gemm_f32<<<gemm_grid, blk, 0, stream>>>(x1, W1, hp, N1, DO, D1);
  // out1 += segment_sum(ew1 * hp[col1], row1)
  scatter_edges<<<edge_grid, blk, 0, stream>>>(hp, ew1, row1, col1, out1, E);
  // out1 = LN(out1)
  ln_rows<<<ln_grid, blk, 0, stream>>>(out1, g1, b1, N1);
}

// Round 2
// 1483.185 us; speedup vs baseline: 2.1786x; 2.1786x over previous
//
#include <hip/hip_runtime.h>
#include <hip/hip_bf16.h>
#include <cstddef>

// ---------------- GEMM: C[M,N] = A[M,K] @ B[K,N], fp32, row-major ----------------
#define BM 128
#define BN 128
#define BK 16
#define TM 8
#define TN 8

__global__ __launch_bounds__(256) void gemm_f32(
    const float* __restrict__ A, const float* __restrict__ B, float* __restrict__ C,
    int M, int N, int K) {
  __shared__ float As[BK][BM];
  __shared__ float Bs[BK][BN];
  const int tid = threadIdx.x;
  const int brow = blockIdx.y * BM;
  const int bcol = blockIdx.x * BN;
  const int tr = (tid / (BN / TN)) * TM;
  const int tc = (tid % (BN / TN)) * TN;
  float acc[TM][TN] = {};

  for (int k0 = 0; k0 < K; k0 += BK) {
    {
      const int m = tid >> 1;
      const int k = (tid & 1) * 8;
      const int gr = brow + m;
      float4 v0 = make_float4(0.f, 0.f, 0.f, 0.f), v1 = v0;
      if (gr < M) {
        const float* p = A + (size_t)gr * K + k0 + k;
        v0 = *(const float4*)p;
        v1 = *(const float4*)(p + 4);
      }
      As[k + 0][m] = v0.x; As[k + 1][m] = v0.y; As[k + 2][m] = v0.z; As[k + 3][m] = v0.w;
      As[k + 4][m] = v1.x; As[k + 5][m] = v1.y; As[k + 6][m] = v1.z; As[k + 7][m] = v1.w;
    }
    {
      const int k = tid >> 4;
      const int n = (tid & 15) * 8;
      const float* p = B + (size_t)(k0 + k) * N + bcol + n;
      float4 v0 = *(const float4*)p;
      float4 v1 = *(const float4*)(p + 4);
      *(float4*)&Bs[k][n] = v0;
      *(float4*)&Bs[k][n + 4] = v1;
    }
    __syncthreads();
#pragma unroll
    for (int k = 0; k < BK; ++k) {
      float a[TM], b[TN];
      *(float4*)&a[0] = *(const float4*)&As[k][tr];
      *(float4*)&a[4] = *(const float4*)&As[k][tr + 4];
      *(float4*)&b[0] = *(const float4*)&Bs[k][tc];
      *(float4*)&b[4] = *(const float4*)&Bs[k][tc + 4];
#pragma unroll
      for (int i = 0; i < TM; i++)
#pragma unroll
        for (int j = 0; j < TN; j++)
          acc[i][j] = fmaf(a[i], b[j], acc[i][j]);
    }
    __syncthreads();
  }

  for (int i = 0; i < TM; i++) {
    const int gr = brow + tr + i;
    if (gr < M) {
      float4* p = (float4*)(C + (size_t)gr * N + bcol + tc);
      p[0] = *(float4*)&acc[i][0];
      p[1] = *(float4*)&acc[i][4];
    }
  }
}

// ---------------- CSR build ----------------
__global__ __launch_bounds__(256) void zero_i32(int* __restrict__ p, int n) {
  int i = blockIdx.x * 256 + threadIdx.x;
  if (i < n) p[i] = 0;
}

__global__ __launch_bounds__(256) void hist_rows(const int* __restrict__ row,
                                                 int* __restrict__ deg, int E) {
  int e = blockIdx.x * 256 + threadIdx.x;
  if (e < E) atomicAdd(&deg[row[e]], 1);
}

// scan1: per-block (chunk=1024) local exclusive scan of deg -> offs, block sum -> partials
__global__ __launch_bounds__(256) void scan1(const int* __restrict__ deg,
                                             int* __restrict__ offs,
                                             int* __restrict__ partials, int n) {
  __shared__ int sh[256];
  const int t = threadIdx.x;
  const int base = blockIdx.x * 1024 + t * 4;
  int v[4];
#pragma unroll
  for (int j = 0; j < 4; j++) v[j] = (base + j < n) ? deg[base + j] : 0;
  const int tsum = v[0] + v[1] + v[2] + v[3];
  sh[t] = tsum;
  __syncthreads();
  for (int off = 1; off < 256; off <<= 1) {
    int x = (t >= off) ? sh[t - off] : 0;
    __syncthreads();
    sh[t] += x;
    __syncthreads();
  }
  if (t == 255) partials[blockIdx.x] = sh[255];
  int run = sh[t] - tsum;  // exclusive prefix of this thread within block
#pragma unroll
  for (int j = 0; j < 4; j++) {
    if (base + j < n) offs[base + j] = run;
    run += v[j];
  }
}

// scan2: serial exclusive scan of partials (small)
__global__ void scan2(int* __restrict__ partials, int nb) {
  if (threadIdx.x == 0 && blockIdx.x == 0) {
    int run = 0;
    for (int i = 0; i < nb; i++) {
      int t = partials[i];
      partials[i] = run;
      run += t;
    }
  }
}

// scan3: add block base; also emit cursor copy and offs[n]=total
__global__ __launch_bounds__(256) void scan3(int* __restrict__ offs,
                                             const int* __restrict__ partials,
                                             int* __restrict__ cur, int n, int total) {
  const int t = threadIdx.x;
  const int base = blockIdx.x * 1024 + t * 4;
  const int add = partials[blockIdx.x];
#pragma unroll
  for (int j = 0; j < 4; j++) {
    const int i = base + j;
    if (i < n) {
      const int v = offs[i] + add;
      offs[i] = v;
      cur[i] = v;
    }
  }
  if (blockIdx.x == 0 && t == 0) offs[n] = total;
}

__global__ __launch_bounds__(256) void bucket_edges(
    const int* __restrict__ row, const int* __restrict__ col, const float* __restrict__ ew,
    int* __restrict__ cur, int* __restrict__ scol, float* __restrict__ sew, int E) {
  int e = blockIdx.x * 256 + threadIdx.x;
  if (e >= E) return;
  const int r = row[e];
  const int pos = atomicAdd(&cur[r], 1);
  scol[pos] = col[e];
  sew[pos] = ew[e];
}

// ---------------- fused aggregate + residual + LayerNorm, one wave per row ----------------
__global__ __launch_bounds__(256) void agg_ln(
    const float* __restrict__ hp, const int* __restrict__ offs,
    const int* __restrict__ scol, const float* __restrict__ sew,
    const float* __restrict__ res, const float* __restrict__ g, const float* __restrict__ b,
    float* __restrict__ out, int nrows) {
  const int wave = threadIdx.x >> 6;
  const int lane = threadIdx.x & 63;
  const int r = blockIdx.x * 4 + wave;
  if (r >= nrows) return;
  const int f4 = lane * 4;

  float4 acc = *(const float4*)(res + (size_t)r * 256 + f4);
  int k = offs[r];
  const int kend = offs[r + 1];
  for (; k + 1 < kend; k += 2) {
    const int c0 = scol[k], c1 = scol[k + 1];
    const float w0 = sew[k], w1 = sew[k + 1];
    const float4 h0 = *(const float4*)(hp + (size_t)c0 * 256 + f4);
    const float4 h1 = *(const float4*)(hp + (size_t)c1 * 256 + f4);
    acc.x += w0 * h0.x + w1 * h1.x;
    acc.y += w0 * h0.y + w1 * h1.y;
    acc.z += w0 * h0.z + w1 * h1.z;
    acc.w += w0 * h0.w + w1 * h1.w;
  }
  if (k < kend) {
    const int c = scol[k];
    const float w = sew[k];
    const float4 h = *(const float4*)(hp + (size_t)c * 256 + f4);
    acc.x += w * h.x; acc.y += w * h.y; acc.z += w * h.z; acc.w += w * h.w;
  }

  float s = acc.x + acc.y + acc.z + acc.w;
#pragma unroll
  for (int m = 32; m >= 1; m >>= 1) s += __shfl_xor(s, m);
  const float mu = s * (1.f / 256.f);
  acc.x -= mu; acc.y -= mu; acc.z -= mu; acc.w -= mu;
  float ss = acc.x * acc.x + acc.y * acc.y + acc.z * acc.z + acc.w * acc.w;
#pragma unroll
  for (int m = 32; m >= 1; m >>= 1) ss += __shfl_xor(ss, m);
  const float rs = rsqrtf(ss * (1.f / 256.f) + 1e-5f);

  const float4 gg = *(const float4*)(g + f4);
  const float4 bb = *(const float4*)(b + f4);
  float4 o;
  o.x = acc.x * rs * gg.x + bb.x;
  o.y = acc.y * rs * gg.y + bb.y;
  o.z = acc.z * rs * gg.z + bb.z;
  o.w = acc.w * rs * gg.w + bb.w;
  *(float4*)(out + (size_t)r * 256 + f4) = o;
}

extern "C" void kernel_launch(void* const* d_in, const int* in_sizes, int n_in,
                              void* d_out, int out_size, void* d_ws, size_t ws_size,
                              hipStream_t stream) {
  const float* x0    = (const float*)d_in[0];
  const float* x1    = (const float*)d_in[1];
  const float* W0    = (const float*)d_in[2];
  const float* W1    = (const float*)d_in[3];
  const float* Wres1 = (const float*)d_in[4];
  const float* g0    = (const float*)d_in[5];
  const float* b0    = (const float*)d_in[6];
  const float* g1    = (const float*)d_in[7];
  const float* b1    = (const float*)d_in[8];
  const float* ew0   = (const float*)d_in[9];
  const float* ew1   = (const float*)d_in[10];
  const int*   row0  = (const int*)d_in[11];
  const int*   col0  = (const int*)d_in[12];
  const int*   row1  = (const int*)d_in[13];
  const int*   col1  = (const int*)d_in[14];
  float* out = (float*)d_out;

  const int N = 50000, D0 = 256, D1 = 512, DO = 256, E = 1600000;
  const int NB = (N + 1023) / 1024;  // 49 scan blocks

  // ws layout (bytes, 16B-aligned)
  char* w = (char*)d_ws;
  float* hp    = (float*)(w);                  // 51,200,000
  int*   scol  = (int*)  (w + 51200000);       //  6,400,000
  float* sew   = (float*)(w + 57600000);       //  6,400,000
  int*   offs  = (int*)  (w + 64000000);       //    200,004 (N+1)
  int*   cur   = (int*)  (w + 64200192);       //    200,000
  int*   deg   = (int*)  (w + 64400384);       //    200,000
  int*   parts = (int*)  (w + 64600576);       //        196

  float* out0 = out;
  float* out1 = out + (size_t)N * DO;

  const dim3 blk(256);
  const dim3 gemm_grid(DO / BN, (N + BM - 1) / BM);
  const dim3 edge_grid((E + 255) / 256);
  const dim3 row_grid((N + 255) / 256);
  const dim3 agg_grid((N + 3) / 4);

  auto run_type = [&](const float* x, const float* W, const int* row, const int* col,
                      const float* ew, const float* res, const float* g, const float* b,
                      float* outp, int K) {
    // CSR build
    zero_i32<<<row_grid, blk, 0, stream>>>(deg, N);
    hist_rows<<<edge_grid, blk, 0, stream>>>(row, deg, E);
    scan1<<<dim3(NB), blk, 0, stream>>>(deg, offs, parts, N);
    scan2<<<dim3(1), dim3(64), 0, stream>>>(parts, NB);
    scan3<<<dim3(NB), blk, 0, stream>>>(offs, parts, cur, N, E);
    bucket_edges<<<edge_grid, blk, 0, stream>>>(row, col, ew, cur, scol, sew, E);
    // projection
    gemm_f32<<<gemm_grid, blk, 0, stream>>>(x, W, hp, N, DO, K);
    // fused aggregate + residual + LN
    agg_ln<<<agg_grid, blk, 0, stream>>>(hp, offs, scol, sew, res, g, b, outp, N);
  };

  // type 0: identity residual (res = x0)
  run_type(x0, W0, row0, col0, ew0, x0, g0, b0, out0, D0);

  // type 1: projected residual — out1 = x1@Wres1 first, then used as res in-place
  gemm_f32<<<gemm_grid, blk, 0, stream>>>(x1, Wres1, out1, N, DO, D1);
  run_type(x1, W1, row1, col1, ew1, out1, g1, b1, out1, D1);
}

// Round 3
// 983.835 us; speedup vs baseline: 3.2843x; 1.5076x over previous
//
#include <hip/hip_runtime.h>
#include <hip/hip_bf16.h>
#include <cstddef>

typedef unsigned short u16;
typedef u16 u16x8 __attribute__((ext_vector_type(8)));
typedef __bf16 bf16x8 __attribute__((ext_vector_type(8)));
typedef float f32x4 __attribute__((ext_vector_type(4)));

__device__ __forceinline__ u16 f2b(float f) {
  unsigned int u = __float_as_uint(f);
  unsigned int r = 0x7FFFu + ((u >> 16) & 1u);
  return (u16)((u + r) >> 16);
}
__device__ __forceinline__ float b2f(u16 u) {
  return __uint_as_float(((unsigned int)u) << 16);
}

// ---------------- bf16 MFMA GEMM: C[M,256] = A[M,K](fp32) @ Wt[256,K](bf16)^T --------
// 128x128 tile, 256 threads = 4 waves in 2x2 quadrants of 64x64.
// A conversion fp32->bf16 fused into LDS staging. XOR-swizzled LDS (c ^= row&7)
// keeps ds_read_b128 at the 8-cycle floor.
template <bool OUT_BF16>
__global__ __launch_bounds__(256) void gemm_bf16(
    const float* __restrict__ A, const u16* __restrict__ Bt, void* __restrict__ Cv,
    int M, int K) {
  __shared__ u16 As[128 * 64];
  __shared__ u16 Bs[128 * 64];
  const int tid = threadIdx.x;
  const int wid = tid >> 6;
  const int lane = tid & 63;
  const int brow = blockIdx.y * 128;
  const int bcol = blockIdx.x * 128;
  const int waveM = (wid >> 1) * 64;
  const int waveN = (wid & 1) * 64;
  const int q = lane >> 4;
  const int rl = lane & 15;

  f32x4 acc[4][4] = {};

  const int arow = tid >> 1;         // 0..127
  const int khalf = (tid & 1) * 32;  // element offset within 64-chunk
  const int garow = brow + arow;
  const bool aok = garow < M;
  const int swz = arow & 7;

  for (int k0 = 0; k0 < K; k0 += 64) {
    {  // stage A (fp32 -> bf16)
      const float* src = A + (size_t)garow * K + k0 + khalf;
      u16* dstrow = As + arow * 64;
#pragma unroll
      for (int j = 0; j < 4; ++j) {
        float4 v0 = make_float4(0.f, 0.f, 0.f, 0.f), v1 = v0;
        if (aok) {
          v0 = *(const float4*)(src + j * 8);
          v1 = *(const float4*)(src + j * 8 + 4);
        }
        u16x8 v = {f2b(v0.x), f2b(v0.y), f2b(v0.z), f2b(v0.w),
                   f2b(v1.x), f2b(v1.y), f2b(v1.z), f2b(v1.w)};
        const int c = (khalf >> 3) + j;
        *(u16x8*)(dstrow + 8 * (c ^ swz)) = v;
      }
    }
    {  // stage Bt (already bf16); Bt row = bcol + arow, always < 256
      const u16* src = Bt + (size_t)(bcol + arow) * K + k0 + khalf;
      u16* dstrow = Bs + arow * 64;
#pragma unroll
      for (int j = 0; j < 4; ++j) {
        u16x8 v = *(const u16x8*)(src + j * 8);
        const int c = (khalf >> 3) + j;
        *(u16x8*)(dstrow + 8 * (c ^ swz)) = v;
      }
    }
    __syncthreads();
#pragma unroll
    for (int ks = 0; ks < 2; ++ks) {
      bf16x8 af[4], bfr[4];
      const int cbase = ks * 4 + q;
#pragma unroll
      for (int i = 0; i < 4; ++i) {
        const int r = waveM + 16 * i + rl;
        af[i] = __builtin_bit_cast(bf16x8,
                 *(const u16x8*)(As + r * 64 + 8 * (cbase ^ (rl & 7))));
      }
#pragma unroll
      for (int j = 0; j < 4; ++j) {
        const int r = waveN + 16 * j + rl;
        bfr[j] = __builtin_bit_cast(bf16x8,
                  *(const u16x8*)(Bs + r * 64 + 8 * (cbase ^ (rl & 7))));
      }
#pragma unroll
      for (int i = 0; i < 4; ++i)
#pragma unroll
        for (int j = 0; j < 4; ++j)
          acc[i][j] = __builtin_amdgcn_mfma_f32_16x16x32_bf16(af[i], bfr[j], acc[i][j], 0, 0, 0);
    }
    __syncthreads();
  }

  // epilogue: C/D layout col=lane&15, row=quad*4+reg (m89/m91-verified)
#pragma unroll
  for (int i = 0; i < 4; ++i) {
#pragma unroll
    for (int reg = 0; reg < 4; ++reg) {
      const int gr = brow + waveM + 16 * i + q * 4 + reg;
      if (gr >= M) continue;
#pragma unroll
      for (int j = 0; j < 4; ++j) {
        const int col = bcol + waveN + 16 * j + rl;
        const float v = acc[i][j][reg];
        if (OUT_BF16) ((u16*)Cv)[(size_t)gr * 256 + col] = f2b(v);
        else          ((float*)Cv)[(size_t)gr * 256 + col] = v;
      }
    }
  }
}

// ---------------- W[K][256] fp32 -> Wt[256][K] bf16 ----------------
__global__ __launch_bounds__(256) void conv_wt(const float* __restrict__ W,
                                               u16* __restrict__ Wt, int K) {
  const int idx = blockIdx.x * 256 + threadIdx.x;  // over K*256
  const int k = idx >> 8;
  const int n = idx & 255;
  if (k < K) Wt[(size_t)n * K + k] = f2b(W[idx]);
}

// ---------------- CSR build ----------------
__global__ __launch_bounds__(256) void zero_i32(int* __restrict__ p, int n) {
  int i = blockIdx.x * 256 + threadIdx.x;
  if (i < n) p[i] = 0;
}

__global__ __launch_bounds__(256) void hist_rows(const int* __restrict__ row,
                                                 int* __restrict__ deg, int E) {
  int e = blockIdx.x * 256 + threadIdx.x;
  if (e < E) atomicAdd(&deg[row[e]], 1);
}

__global__ __launch_bounds__(256) void scan1(const int* __restrict__ deg,
                                             int* __restrict__ offs,
                                             int* __restrict__ partials, int n) {
  __shared__ int sh[256];
  const int t = threadIdx.x;
  const int base = blockIdx.x * 1024 + t * 4;
  int v[4];
#pragma unroll
  for (int j = 0; j < 4; j++) v[j] = (base + j < n) ? deg[base + j] : 0;
  const int tsum = v[0] + v[1] + v[2] + v[3];
  sh[t] = tsum;
  __syncthreads();
  for (int off = 1; off < 256; off <<= 1) {
    int x = (t >= off) ? sh[t - off] : 0;
    __syncthreads();
    sh[t] += x;
    __syncthreads();
  }
  if (t == 255) partials[blockIdx.x] = sh[255];
  int run = sh[t] - tsum;
#pragma unroll
  for (int j = 0; j < 4; j++) {
    if (base + j < n) offs[base + j] = run;
    run += v[j];
  }
}

__global__ void scan2(int* __restrict__ partials, int nb) {
  if (threadIdx.x == 0 && blockIdx.x == 0) {
    int run = 0;
    for (int i = 0; i < nb; i++) {
      int t = partials[i];
      partials[i] = run;
      run += t;
    }
  }
}

__global__ __launch_bounds__(256) void scan3(int* __restrict__ offs,
                                             const int* __restrict__ partials,
                                             int* __restrict__ cur, int n, int total) {
  const int t = threadIdx.x;
  const int base = blockIdx.x * 1024 + t * 4;
  const int add = partials[blockIdx.x];
#pragma unroll
  for (int j = 0; j < 4; j++) {
    const int i = base + j;
    if (i < n) {
      const int v = offs[i] + add;
      offs[i] = v;
      cur[i] = v;
    }
  }
  if (blockIdx.x == 0 && t == 0) offs[n] = total;
}

__global__ __launch_bounds__(256) void bucket_edges(
    const int* __restrict__ row, const int* __restrict__ col, const float* __restrict__ ew,
    int* __restrict__ cur, int* __restrict__ scol, float* __restrict__ sew, int E) {
  int e = blockIdx.x * 256 + threadIdx.x;
  if (e >= E) return;
  const int r = row[e];
  const int pos = atomicAdd(&cur[r], 1);
  scol[pos] = col[e];
  sew[pos] = ew[e];
}

// ------- fused aggregate (bf16 hp gather) + residual + LayerNorm, 1 wave/row -------
__global__ __launch_bounds__(256) void agg_ln(
    const u16* __restrict__ hpb, const int* __restrict__ offs,
    const int* __restrict__ scol, const float* __restrict__ sew,
    const float* __restrict__ res, const float* __restrict__ g, const float* __restrict__ b,
    float* __restrict__ out, int nrows) {
  const int wave = threadIdx.x >> 6;
  const int lane = threadIdx.x & 63;
  const int r = blockIdx.x * 4 + wave;
  if (r >= nrows) return;
  const int f4 = lane * 4;

  float4 acc = *(const float4*)(res + (size_t)r * 256 + f4);
  int k = offs[r];
  const int kend = offs[r + 1];
  for (; k + 3 < kend; k += 4) {
    const int c0 = scol[k], c1 = scol[k + 1], c2 = scol[k + 2], c3 = scol[k + 3];
    const float w0 = sew[k], w1 = sew[k + 1], w2 = sew[k + 2], w3 = sew[k + 3];
    const ushort4 h0 = *(const ushort4*)(hpb + (size_t)c0 * 256 + f4);
    const ushort4 h1 = *(const ushort4*)(hpb + (size_t)c1 * 256 + f4);
    const ushort4 h2 = *(const ushort4*)(hpb + (size_t)c2 * 256 + f4);
    const ushort4 h3 = *(const ushort4*)(hpb + (size_t)c3 * 256 + f4);
    acc.x += w0 * b2f(h0.x) + w1 * b2f(h1.x) + w2 * b2f(h2.x) + w3 * b2f(h3.x);
    acc.y += w0 * b2f(h0.y) + w1 * b2f(h1.y) + w2 * b2f(h2.y) + w3 * b2f(h3.y);
    acc.z += w0 * b2f(h0.z) + w1 * b2f(h1.z) + w2 * b2f(h2.z) + w3 * b2f(h3.z);
    acc.w += w0 * b2f(h0.w) + w1 * b2f(h1.w) + w2 * b2f(h2.w) + w3 * b2f(h3.w);
  }
  for (; k < kend; ++k) {
    const int c = scol[k];
    const float w = sew[k];
    const ushort4 h = *(const ushort4*)(hpb + (size_t)c * 256 + f4);
    acc.x += w * b2f(h.x); acc.y += w * b2f(h.y);
    acc.z += w * b2f(h.z); acc.w += w * b2f(h.w);
  }

  float s = acc.x + acc.y + acc.z + acc.w;
#pragma unroll
  for (int m = 32; m >= 1; m >>= 1) s += __shfl_xor(s, m);
  const float mu = s * (1.f / 256.f);
  acc.x -= mu; acc.y -= mu; acc.z -= mu; acc.w -= mu;
  float ss = acc.x * acc.x + acc.y * acc.y + acc.z * acc.z + acc.w * acc.w;
#pragma unroll
  for (int m = 32; m >= 1; m >>= 1) ss += __shfl_xor(ss, m);
  const float rs = rsqrtf(ss * (1.f / 256.f) + 1e-5f);

  const float4 gg = *(const float4*)(g + f4);
  const float4 bb = *(const float4*)(b + f4);
  float4 o;
  o.x = acc.x * rs * gg.x + bb.x;
  o.y = acc.y * rs * gg.y + bb.y;
  o.z = acc.z * rs * gg.z + bb.z;
  o.w = acc.w * rs * gg.w + bb.w;
  *(float4*)(out + (size_t)r * 256 + f4) = o;
}

extern "C" void kernel_launch(void* const* d_in, const int* in_sizes, int n_in,
                              void* d_out, int out_size, void* d_ws, size_t ws_size,
                              hipStream_t stream) {
  const float* x0    = (const float*)d_in[0];
  const float* x1    = (const float*)d_in[1];
  const float* W0    = (const float*)d_in[2];
  const float* W1    = (const float*)d_in[3];
  const float* Wres1 = (const float*)d_in[4];
  const float* g0    = (const float*)d_in[5];
  const float* b0    = (const float*)d_in[6];
  const float* g1    = (const float*)d_in[7];
  const float* b1    = (const float*)d_in[8];
  const float* ew0   = (const float*)d_in[9];
  const float* ew1   = (const float*)d_in[10];
  const int*   row0  = (const int*)d_in[11];
  const int*   col0  = (const int*)d_in[12];
  const int*   row1  = (const int*)d_in[13];
  const int*   col1  = (const int*)d_in[14];
  float* out = (float*)d_out;

  const int N = 50000, D0 = 256, D1 = 512, DO = 256, E = 1600000;
  const int NB = (N + 1023) / 1024;

  // ws layout (bytes, 16B-aligned)
  char* w = (char*)d_ws;
  u16*   hpb   = (u16*)  (w);                  // 25,600,000
  u16*   wtb   = (u16*)  (w + 25600000);       //    262,144 (max 512x256 bf16)
  int*   scol  = (int*)  (w + 25862144);       //  6,400,000
  float* sew   = (float*)(w + 32262144);       //  6,400,000
  int*   offs  = (int*)  (w + 38662144);       //    200,004 (N+1)
  int*   cur   = (int*)  (w + 38862208);       //    200,000
  int*   deg   = (int*)  (w + 39062208);       //    200,000
  int*   parts = (int*)  (w + 39262208);       //        196

  float* out0 = out;
  float* out1 = out + (size_t)N * DO;

  const dim3 blk(256);
  const dim3 gemm_grid(2, (N + 127) / 128);
  const dim3 edge_grid((E + 255) / 256);
  const dim3 row_grid((N + 255) / 256);
  const dim3 agg_grid((N + 3) / 4);

  auto build_csr = [&](const int* row, const int* col, const float* ew) {
    zero_i32<<<row_grid, blk, 0, stream>>>(deg, N);
    hist_rows<<<edge_grid, blk, 0, stream>>>(row, deg, E);
    scan1<<<dim3(NB), blk, 0, stream>>>(deg, offs, parts, N);
    scan2<<<dim3(1), dim3(64), 0, stream>>>(parts, NB);
    scan3<<<dim3(NB), blk, 0, stream>>>(offs, parts, cur, N, E);
    bucket_edges<<<edge_grid, blk, 0, stream>>>(row, col, ew, cur, scol, sew, E);
  };

  // ---- type 0: identity residual ----
  build_csr(row0, col0, ew0);
  conv_wt<<<dim3(D0), blk, 0, stream>>>(W0, wtb, D0);
  gemm_bf16<true><<<gemm_grid, blk, 0, stream>>>(x0, wtb, hpb, N, D0);
  agg_ln<<<agg_grid, blk, 0, stream>>>(hpb, offs, scol, sew, x0, g0, b0, out0, N);

  // ---- type 1: projected residual ----
  conv_wt<<<dim3(D1), blk, 0, stream>>>(Wres1, wtb, D1);
  gemm_bf16<false><<<gemm_grid, blk, 0, stream>>>(x1, wtb, out1, N, D1);
  build_csr(row1, col1, ew1);
  conv_wt<<<dim3(D1), blk, 0, stream>>>(W1, wtb, D1);
  gemm_bf16<true><<<gemm_grid, blk, 0, stream>>>(x1, wtb, hpb, N, D1);
  agg_ln<<<agg_grid, blk, 0, stream>>>(hpb, offs, scol, sew, out1, g1, b1, out1, N);
}